// Round 6
// baseline (106.977 us; speedup 1.0000x reference)
//
#include <hip/hip_runtime.h>
#include <stdint.h>

typedef unsigned int u32;
typedef unsigned long long u64;

#define MOD_P 2013265921u

// uint2 table offsets (index in uint2 units): (value, shoup) pairs
#define T_A      0        // w^{(i>>7)*(i&127)}        [ka][jc] product table, 16384
#define T_B      16384    // (w^128)^{(i>>7)*(i&127)}  [kb][jc] product table, 16384
#define T_W128P  32768    // (w^128)^i, i<16384
#define T_RP     49152    // (w^16384)^i, i<64  (order-128 stage roots)
#define T_CLP    49216    // c^i, i<16384       (coset low)
#define T_CHP    65600    // c^(16384 i), i<128 (coset high)
#define T_NINV   65728    // (n^-1)

__device__ __forceinline__ u32 mul64mod(u32 a, u32 b){ return (u32)((u64)a * b % MOD_P); }

__device__ u32 powmod(u32 b, u32 e){
  u32 r = 1;
  while (e){ if (e & 1) r = mul64mod(r, b); b = mul64mod(b, b); e >>= 1; }
  return r;
}

__device__ __forceinline__ u32 shoup_of(u32 v){ return (u32)(((u64)v << 32) / MOD_P); }

// reduce a in [0,2P) to [0,P): unsigned-wrap min trick (v_sub + v_min_u32)
__device__ __forceinline__ u32 redP(u32 a){
  u32 b = a - MOD_P;
  return b < a ? b : a;
}

// Shoup modular multiply; valid for ANY a < 2^32 (w < P): r = a*w mod P in [0,P)
__device__ __forceinline__ u32 mul_shoup(u32 a, uint2 t){
  u32 q = __umulhi(a, t.y);
  u32 r = a * t.x - q * MOD_P;          // exact mod 2^32, true value < 2P
  return redP(r);
}

__device__ __forceinline__ constexpr int rev4(int m){
  return ((m&1)<<3) | ((m&2)<<1) | ((m&4)>>1) | ((m&8)>>3);
}

// DIF butterfly: (x,y) -> (x+y mod P, (x-y)*t mod P); inputs in [0,P)
__device__ __forceinline__ void bf(u32 &x, u32 &y, uint2 t){
  u32 s = redP(x + y);
  u32 d = x - y + MOD_P;                // in (0,2P) — mul_shoup absorbs
  x = s; y = mul_shoup(d, t);
}
// last stage, twiddle=1: y left in [0,2P) (consumer must absorb or redP)
__device__ __forceinline__ void bf0(u32 &x, u32 &y){
  u32 s = redP(x + y);
  u32 d = x - y + MOD_P;
  x = s; y = d;
}

// phase-1: thread rows r = b + 8m (m=0..15), DIF stages h=64,32,16,8
__device__ __forceinline__ void stages_p1(u32 v[16], int b, const uint2* __restrict__ twl){
  #pragma unroll
  for (int m = 0; m < 8; ++m) bf(v[m], v[m+8], twl[b + 8*m]);               // s=6
  #pragma unroll
  for (int g = 0; g < 2; ++g)
    #pragma unroll
    for (int m = 0; m < 4; ++m) bf(v[g*8+m], v[g*8+m+4], twl[(b + 8*m) << 1]); // s=5
  #pragma unroll
  for (int g = 0; g < 4; ++g)
    #pragma unroll
    for (int m = 0; m < 2; ++m) bf(v[g*4+m], v[g*4+m+2], twl[(b + 8*m) << 2]); // s=4
  #pragma unroll
  for (int k = 0; k < 8; ++k) bf(v[2*k], v[2*k+1], twl[b << 3]);            // s=3
}
// phase-2: thread rows r = 16b + m, DIF stages h=4,2,1
__device__ __forceinline__ void stages_p2(u32 v[16], const uint2* __restrict__ twl){
  #pragma unroll
  for (int g = 0; g < 2; ++g)
    #pragma unroll
    for (int m = 0; m < 4; ++m) bf(v[g*8+m], v[g*8+m+4], twl[m << 4]);      // s=2
  #pragma unroll
  for (int g = 0; g < 4; ++g)
    #pragma unroll
    for (int m = 0; m < 2; ++m) bf(v[g*4+m], v[g*4+m+2], twl[m << 5]);      // s=1
  #pragma unroll
  for (int k = 0; k < 8; ++k) bf0(v[2*k], v[2*k+1]);                        // s=0 (e=0)
}

// ---------------- table generation (per launch; reads direction flag) -------
extern "C" __global__ void k_gen(uint2* __restrict__ tw, const int* __restrict__ f_intt){
  const int idx = blockIdx.x * 256 + threadIdx.x;   // 0..16383
  const int intt = f_intt[0];
  u32 w = powmod(31u, (MOD_P - 1) >> 21);     // primitive 2^21-th root
  if (intt) w = powmod(w, MOD_P - 2);
  const u32 w128 = powmod(w, 128u);
  const int hi = idx >> 7, lo = idx & 127;

  u32 a = powmod(w, (u32)(hi * lo));
  tw[T_A + idx] = make_uint2(a, shoup_of(a));
  u32 b = powmod(w128, (u32)(hi * lo));
  tw[T_B + idx] = make_uint2(b, shoup_of(b));
  u32 v2 = powmod(w128, (u32)idx);
  tw[T_W128P + idx] = make_uint2(v2, shoup_of(v2));
  u32 c = intt ? powmod(7u, MOD_P - 2) : 7u;
  u32 cv = powmod(c, (u32)idx);
  tw[T_CLP + idx] = make_uint2(cv, shoup_of(cv));
  if (idx < 128){
    u32 h = powmod(c, (u32)idx << 14);
    tw[T_CHP + idx] = make_uint2(h, shoup_of(h));
  }
  if (idx < 64){
    u32 rv = powmod(powmod(w, 1u << 14), (u32)idx);
    tw[T_RP + idx] = make_uint2(rv, shoup_of(rv));
  }
  if (idx == 0){
    u32 ninv = powmod(1u << 21, MOD_P - 2);
    tw[T_NINV] = make_uint2(ninv, shoup_of(ninv));
  }
}

// ---------------- pass A: NTT over ja (stride 16384), d_in -> d_out ---------
// grid: batch*128, WG=(batch, jb); thread=(b, jc): 16 elems in reg
extern "C" __global__ void __launch_bounds__(1024, 8) k_passA(
    const u32* __restrict__ x, u32* __restrict__ y, const uint2* __restrict__ tw,
    const int* __restrict__ f_intt, const int* __restrict__ f_coset)
{
  __shared__ u32 lds[16384];              // [128 rows][128 cols], row access only
  const int wg = blockIdx.x;
  const int jb = wg & 127;
  const int batch = wg >> 7;
  const int t = threadIdx.x;
  const int jc = t & 127;
  const int b = __builtin_amdgcn_readfirstlane(t >> 7);   // 0..7, wave-uniform
  const u32* xb = x + ((size_t)batch << 21);
  u32* yb = y + ((size_t)batch << 21);
  const uint2* twl = tw + T_RP;

  u32 v[16];
  #pragma unroll
  for (int m = 0; m < 16; ++m){
    u32 a = xb[((size_t)(b + 8*m) << 14) + (jb << 7) + jc];
    v[m] = redP(a);
  }
  if ((f_intt[0] == 0) && (f_coset[0] != 0)){
    uint2 cl = tw[T_CLP + (jb << 7) + jc];
    #pragma unroll
    for (int m = 0; m < 16; ++m){
      v[m] = mul_shoup(v[m], cl);
      v[m] = mul_shoup(v[m], tw[T_CHP + b + 8*m]);
    }
  }
  stages_p1(v, b, twl);
  #pragma unroll
  for (int m = 0; m < 16; ++m) lds[((b + 8*m) << 7) | jc] = v[m];
  __syncthreads();
  #pragma unroll
  for (int m = 0; m < 16; ++m) v[m] = lds[((16*b + m) << 7) | jc];
  stages_p2(v, twl);
  const int rb = ((b&1)<<2) | (b&2) | ((b&4)>>2);          // rev3(b)
  #pragma unroll
  for (int m = 0; m < 16; ++m){
    const int ka = (rev4(m) << 3) | rb;                    // br7(16b+m)
    u32 vv = mul_shoup(v[m], tw[T_A + (ka << 7) + jc]);    // absorbs [0,2P)
    vv = mul_shoup(vv, tw[T_W128P + ka * jb]);             // wave-uniform (s_load)
    yb[((size_t)ka << 14) + (jb << 7) + jc] = vv;
  }
}

// ---------------- pass B: NTT over jb (contiguous slab, in-place) -----------
extern "C" __global__ void __launch_bounds__(1024, 8) k_passB(
    u32* __restrict__ y, const uint2* __restrict__ tw)
{
  __shared__ u32 lds[16384];
  const int wg = blockIdx.x;
  const int ka = wg & 127;
  const int batch = wg >> 7;
  const int t = threadIdx.x;
  const int jc = t & 127;
  const int b = __builtin_amdgcn_readfirstlane(t >> 7);
  u32* yb = y + ((size_t)batch << 21) + ((size_t)ka << 14);
  const uint2* twl = tw + T_RP;

  u32 v[16];
  #pragma unroll
  for (int m = 0; m < 16; ++m) v[m] = yb[((b + 8*m) << 7) + jc];
  stages_p1(v, b, twl);
  #pragma unroll
  for (int m = 0; m < 16; ++m) lds[((b + 8*m) << 7) | jc] = v[m];
  __syncthreads();
  #pragma unroll
  for (int m = 0; m < 16; ++m) v[m] = lds[((16*b + m) << 7) | jc];
  stages_p2(v, twl);
  const int rb = ((b&1)<<2) | (b&2) | ((b&4)>>2);
  #pragma unroll
  for (int m = 0; m < 16; ++m){
    const int kb = (rev4(m) << 3) | rb;
    u32 vv = mul_shoup(v[m], tw[T_B + (kb << 7) + jc]);    // absorbs [0,2P)
    yb[(kb << 7) + jc] = vv;
  }
}

// ------- pass C: NTT over jc + in-place plane transpose to final order ------
// grid: batch*128, WG=(batch, kb)
// LDS tile [row=jc(128)][col=ka(128)] with XOR swizzle col^(row>>2): 2-way max
__device__ __forceinline__ int cidx(int row, int a){
  return (row << 7) | (a ^ (row >> 2));
}
extern "C" __global__ void __launch_bounds__(1024, 8) k_passC(
    u32* __restrict__ y, const uint2* __restrict__ tw,
    const int* __restrict__ f_intt, const int* __restrict__ f_coset)
{
  __shared__ u32 lds[16384];
  const int wg = blockIdx.x;
  const int kb = wg & 127;
  const int batch = wg >> 7;
  u32* yb = y + ((size_t)batch << 21);
  const u32* base = yb + (kb << 7);
  const int t = threadIdx.x;
  {   // stage-in: transpose [ka][jc] -> LDS[jc][ka]
    const int q = t & 31;                // jc quad
    const int rr = t >> 5;               // 0..31
    #pragma unroll
    for (int i = 0; i < 4; ++i){
      int kaL = rr + 32*i;
      uint4 v4 = *(const uint4*)(base + ((size_t)kaL << 14) + (q << 2));
      lds[cidx(4*q+0, kaL)] = v4.x;
      lds[cidx(4*q+1, kaL)] = v4.y;
      lds[cidx(4*q+2, kaL)] = v4.z;
      lds[cidx(4*q+3, kaL)] = v4.w;
    }
  }
  __syncthreads();
  const int a = t & 127;
  const int b = __builtin_amdgcn_readfirstlane(t >> 7);
  const uint2* twl = tw + T_RP;
  u32 v[16];
  #pragma unroll
  for (int m = 0; m < 16; ++m) v[m] = lds[cidx(b + 8*m, a)];
  stages_p1(v, b, twl);
  #pragma unroll
  for (int m = 0; m < 16; ++m) lds[cidx(b + 8*m, a)] = v[m];
  __syncthreads();
  #pragma unroll
  for (int m = 0; m < 16; ++m) v[m] = lds[cidx(16*b + m, a)];
  stages_p2(v, twl);
  const int rb = ((b&1)<<2) | (b&2) | ((b&4)>>2);
  const int intt = f_intt[0];
  const int coset = f_coset[0];
  #pragma unroll
  for (int m = 0; m < 16; ++m){
    const int kc = (rev4(m) << 3) | rb;
    u32 vv = v[m];
    if (intt){
      vv = mul_shoup(vv, tw[T_NINV]);                      // absorbs [0,2P)
      if (coset){
        vv = mul_shoup(vv, tw[T_CLP + (kb << 7) + a]);
        vv = mul_shoup(vv, tw[T_CHP + kc]);
      }
    } else {
      vv = redP(vv);                                       // bf0 leaves [0,2P)
    }
    yb[((size_t)kc << 14) + (kb << 7) + a] = vv;   // flat = ka + 128*kb + 16384*kc
  }
}

extern "C" void kernel_launch(void* const* d_in, const int* in_sizes, int n_in,
                              void* d_out, int out_size, void* d_ws, size_t ws_size,
                              hipStream_t stream)
{
  const u32* x = (const u32*)d_in[0];
  const int* f_intt  = (const int*)d_in[1];
  const int* f_coset = (const int*)d_in[2];
  u32* y   = (u32*)d_out;
  uint2* tw = (uint2*)d_ws;
  const int batch = in_sizes[0] >> 21;     // 8
  const int nwg = batch << 7;              // 1024 workgroups per pass

  k_gen  <<<64,   256, 0, stream>>>(tw, f_intt);
  k_passA<<<nwg, 1024, 0, stream>>>(x, y, tw, f_intt, f_coset);
  k_passB<<<nwg, 1024, 0, stream>>>(y, tw);
  k_passC<<<nwg, 1024, 0, stream>>>(y, tw, f_intt, f_coset);
}